// Round 6
// baseline (90.537 us; speedup 1.0000x reference)
//
#include <hip/hip_runtime.h>

#define EPS 1e-5f
#define TEMP 50.0f
#define CCH 64
#define HH 128
#define WW 128
#define HWSZ (HH * WW)
#define CEPS2 (CCH * EPS * EPS)

#define IT 8            // interior tile: 8x8 pixels
#define HT 12           // halo tile: 12x12
#define HPX (HT * HT)   // 144 halo pixels
#define HPAD 145        // pad px-dim: 4*145 = 4 mod 32 words, so the
                        // half0/half1 lane interleave covers all 32 banks

typedef _Float16 h16;
typedef h16 h2v __attribute__((ext_vector_type(2)));
typedef h16 h8v __attribute__((ext_vector_type(8)));
union H8 { h8v v; h2v p[4]; };

__device__ __forceinline__ float fdot2(h2v a, h2v b, float c) {
#if __has_builtin(__builtin_amdgcn_fdot2)
    return __builtin_amdgcn_fdot2(a, b, c, false);   // v_dot2_f32_f16
#else
    return c + (float)a[0] * (float)b[0] + (float)a[1] * (float)b[1];
#endif
}

// Block: 128 threads = 2 waves. thread t -> pixel (t>>1), channel-half (t&1).
// Dot reduction across halves = shfl_xor(1) within a lane pair: no LDS, no
// barrier. Softmax computed redundantly per thread in registers.
__global__ __launch_bounds__(128) void rv_fused(const float* __restrict__ x,
                                                float* __restrict__ out) {
    __shared__ h8v  tile[8][HPAD];   // 18560 B: [channel-quad][halo px]
    __shared__ float sh_q[HPX];      // 576 B: per-halo-pixel raw sumsq

    const int t  = threadIdx.x;
    const int w0 = blockIdx.x * IT;
    const int h0 = blockIdx.y * IT;
    const int b  = blockIdx.z;
    const float* xb = x + (size_t)b * (CCH * HWSZ);

    // ---- Stage zero-padded halo: 8 quads x 144 px = 1152 h8v, 9 iters ----
#pragma unroll
    for (int it = 0; it < 9; ++it) {
        int k = it * 128 + t;            // 0..1151
        int hq = k / HPX;                // 0..7 (8 channels each)
        int px = k - hq * HPX;
        int row = px / HT;
        int col = px - row * HT;
        int gh = h0 + row - 2;
        int gw = w0 + col - 2;
        float vv[8] = {0.f, 0.f, 0.f, 0.f, 0.f, 0.f, 0.f, 0.f};
        if (gh >= 0 && gh < HH && gw >= 0 && gw < WW) {
            const float* p = xb + (size_t)(hq * 8) * HWSZ + gh * WW + gw;
#pragma unroll
            for (int j = 0; j < 8; ++j) vv[j] = p[j * HWSZ];
        }
        h8v hv;
#pragma unroll
        for (int j = 0; j < 8; ++j) hv[j] = (h16)vv[j];
        tile[hq][px] = hv;               // contiguous b128, conflict-free
    }
    __syncthreads();

    // ---- Per-halo-pixel sumsq q (from the SAME rounded f16 values) ----
    for (int idx = t; idx < HPX; idx += 128) {
        float q = 0.f;
#pragma unroll
        for (int hq = 0; hq < 8; ++hq) {
            H8 u; u.v = tile[hq][idx];
#pragma unroll
            for (int j = 0; j < 4; ++j) q = fdot2(u.p[j], u.p[j], q);
        }
        sh_q[idx] = q;
    }
    // (visibility covered by the __syncthreads after phase 1)

    const int half = t & 1;              // channel half: quads 4*half..4*half+3
    const int pix  = t >> 1;             // 0..63
    const int r    = pix >> 3;
    const int c    = pix & 7;
    const int cpx  = (r + 2) * HT + (c + 2);

    // ---- Phase 1: partial dots over this half's 32 channels ----
    H8 ctr[4];
#pragma unroll
    for (int g = 0; g < 4; ++g) ctr[g].v = tile[4 * half + g][cpx];

    float D[25];
#pragma unroll
    for (int dr = 0; dr < 5; ++dr) {
#pragma unroll
        for (int dc = 0; dc < 5; ++dc) {
            const int npx = (r + dr) * HT + (c + dc);
            float d = 0.f;
#pragma unroll
            for (int g = 0; g < 4; ++g) {
                H8 a; a.v = tile[4 * half + g][npx];
#pragma unroll
                for (int j = 0; j < 4; ++j) d = fdot2(ctr[g].p[j], a.p[j], d);
            }
            D[dr * 5 + dc] = d;
        }
    }
    // Full 64-ch dots: add the partner half's partials (in-wave lane pair).
#pragma unroll
    for (int n = 0; n < 25; ++n) D[n] += __shfl_xor(D[n], 1);

    __syncthreads();                     // sh_q writes -> reads below

    // ---- Softmax in registers (every thread, redundantly per pair) ----
    // EPS*(s_p+s_q) dot terms dropped: in-bounds shift < 1e-3 on logits;
    // zero-padded OOB neighbors have weight <= e^-25 vs center either way.
    const float N2c = sh_q[cpx] + CEPS2;
    float lg[25];
    float m = -1e30f;
#pragma unroll
    for (int dr = 0; dr < 5; ++dr) {
#pragma unroll
        for (int dc = 0; dc < 5; ++dc) {
            const int n = dr * 5 + dc;
            const int npx = (r + dr) * HT + (c + dc);
            const float N2n = sh_q[npx] + CEPS2;
            const float sim = (D[n] + CEPS2) * rsqrtf(N2n * N2c);
            lg[n] = TEMP * sim;
            m = fmaxf(m, lg[n]);
        }
    }
    float wei[25];
    float sum = 0.f;
#pragma unroll
    for (int n = 0; n < 25; ++n) {
        wei[n] = __expf(lg[n] - m);
        sum += wei[n];
    }
    const float rs = 1.f / sum;
#pragma unroll
    for (int n = 0; n < 25; ++n) wei[n] *= rs;

    // ---- Phase 2: weighted sums for this half's 32 channels ----
    float acc[32];
#pragma unroll
    for (int j = 0; j < 32; ++j) acc[j] = EPS;
#pragma unroll
    for (int dr = 0; dr < 5; ++dr) {
#pragma unroll
        for (int dc = 0; dc < 5; ++dc) {
            const int npx = (r + dr) * HT + (c + dc);
            const float wn = wei[dr * 5 + dc];
#pragma unroll
            for (int g = 0; g < 4; ++g) {
                H8 a; a.v = tile[4 * half + g][npx];
#pragma unroll
                for (int j = 0; j < 8; ++j)
                    acc[g * 8 + j] = fmaf(wn, (float)a.v[j], acc[g * 8 + j]);
            }
        }
    }

    const size_t obase = (size_t)b * (CCH * HWSZ)
                       + (size_t)(32 * half) * HWSZ
                       + (h0 + r) * WW + (w0 + c);
#pragma unroll
    for (int j = 0; j < 32; ++j) {
        out[obase + (size_t)j * HWSZ] = acc[j];
    }
}

extern "C" void kernel_launch(void* const* d_in, const int* in_sizes, int n_in,
                              void* d_out, int out_size, void* d_ws, size_t ws_size,
                              hipStream_t stream) {
    const float* x = (const float*)d_in[0];
    float* outp = (float*)d_out;
    rv_fused<<<dim3(WW / IT, HH / IT, 4), dim3(128, 1, 1), 0, stream>>>(x, outp);
}

// Round 7
// 83.788 us; speedup vs baseline: 1.0805x; 1.0805x over previous
//
#include <hip/hip_runtime.h>

#define EPS 1e-5f
#define TEMP 50.0f
#define CCH 64
#define HH 128
#define WW 128
#define HWSZ (HH * WW)
#define CEPS2 (CCH * EPS * EPS)

#define IT 8            // interior tile: 8x8 pixels
#define HT 12           // halo tile: 12x12
#define HPX (HT * HT)   // 144 halo pixels
#define HPAD 145        // h8v stride: 580 words = 4 mod 32 -> q-groups of 8
                        // lanes cover all 32 banks (conflict-free b128)

typedef _Float16 h16;
typedef h16 h2v __attribute__((ext_vector_type(2)));
typedef h16 h8v __attribute__((ext_vector_type(8)));
union H8 { h8v v; h2v p[4]; };

__device__ __forceinline__ float fdot2(h2v a, h2v b, float c) {
#if __has_builtin(__builtin_amdgcn_fdot2)
    return __builtin_amdgcn_fdot2(a, b, c, false);   // v_dot2_f32_f16
#else
    return c + (float)a[0] * (float)b[0] + (float)a[1] * (float)b[1];
#endif
}

// ---- Kernel A: [B][C][H][W] f32 -> [B][H][W][C] f16 (channel-last) ----
#define TP_PAD 72       // h16 row stride: 144 B, 16B-aligned, conflict-light
__global__ __launch_bounds__(256) void rv_transpose(const float* __restrict__ x,
                                                    h16* __restrict__ xt) {
    __shared__ h16 buf[WW][TP_PAD];          // 18432 B
    const int t = threadIdx.x;
    const int h = blockIdx.x;
    const int b = blockIdx.y;
    const float* src = x + (size_t)b * (CCH * HWSZ) + h * WW;
#pragma unroll 8
    for (int i = 0; i < 32; ++i) {           // 64 ch x 128 w / 256 threads
        int k = i * 256 + t;
        int c = k >> 7;                      // coalesced: w fast across lanes
        int w = k & 127;
        buf[w][c] = (h16)src[(size_t)c * HWSZ + w];
    }
    __syncthreads();
    h16* dst = xt + (size_t)(b * HH + h) * WW * CCH;
#pragma unroll
    for (int j = 0; j < 4; ++j) {            // 128 px x 8 quads / 256 threads
        int idx = j * 256 + t;
        int w = idx >> 3;
        int q = idx & 7;                     // q fast: contiguous b128 stores
        h8v v = *(const h8v*)&buf[w][q * 8];
        *(h8v*)&dst[(size_t)w * CCH + q * 8] = v;
    }
}

// ---- Kernel B: fused dots/softmax/weighted-sum from channel-last f16 ----
// Block: 128 threads = 2 waves. thread t -> pixel (t>>1), channel-half (t&1).
__global__ __launch_bounds__(128) void rv_fused(const h16* __restrict__ xt,
                                                float* __restrict__ out) {
    __shared__ h8v  tile[8][HPAD];   // 18560 B
    __shared__ float sh_q[HPX];      // 576 B

    const int t  = threadIdx.x;
    const int w0 = blockIdx.x * IT;
    const int h0 = blockIdx.y * IT;
    const int b  = blockIdx.z;

    // ---- Stage: 144 px x 8 quads, q-fast lanes => 1KB-contiguous global
    // loads per wave, conflict-free b128 LDS writes (HPAD=145). ----
#pragma unroll
    for (int it = 0; it < 9; ++it) {
        int k = it * 128 + t;            // 0..1151
        int q  = k & 7;
        int px = k >> 3;                 // 0..143
        int row = px / HT;
        int col = px - row * HT;
        int gh = h0 + row - 2;
        int gw = w0 + col - 2;
        h8v v = {};
        if (gh >= 0 && gh < HH && gw >= 0 && gw < WW) {
            v = *(const h8v*)&xt[((size_t)(b * HH + gh) * WW + gw) * CCH + q * 8];
        }
        tile[q][px] = v;
    }
    __syncthreads();

    // ---- Per-halo-pixel sumsq ----
    for (int idx = t; idx < HPX; idx += 128) {
        float q = 0.f;
#pragma unroll
        for (int hq = 0; hq < 8; ++hq) {
            H8 u; u.v = tile[hq][idx];
#pragma unroll
            for (int j = 0; j < 4; ++j) q = fdot2(u.p[j], u.p[j], q);
        }
        sh_q[idx] = q;
    }

    const int half = t & 1;              // quads 4*half .. 4*half+3
    const int pix  = t >> 1;
    const int r    = pix >> 3;
    const int c    = pix & 7;
    const int cpx  = (r + 2) * HT + (c + 2);

    // ---- Phase 1: partial dots over this half's 32 channels ----
    H8 ctr[4];
#pragma unroll
    for (int g = 0; g < 4; ++g) ctr[g].v = tile[4 * half + g][cpx];

    float D[25];
#pragma unroll
    for (int dr = 0; dr < 5; ++dr) {
#pragma unroll
        for (int dc = 0; dc < 5; ++dc) {
            const int npx = (r + dr) * HT + (c + dc);
            float d = 0.f;
#pragma unroll
            for (int g = 0; g < 4; ++g) {
                H8 a; a.v = tile[4 * half + g][npx];
#pragma unroll
                for (int j = 0; j < 4; ++j) d = fdot2(ctr[g].p[j], a.p[j], d);
            }
            D[dr * 5 + dc] = d;
        }
    }
#pragma unroll
    for (int n = 0; n < 25; ++n) D[n] += __shfl_xor(D[n], 1);

    __syncthreads();                     // sh_q visibility

    // ---- Softmax in registers (redundant per lane pair) ----
    const float N2c = sh_q[cpx] + CEPS2;
    float lg[25];
    float m = -1e30f;
#pragma unroll
    for (int dr = 0; dr < 5; ++dr) {
#pragma unroll
        for (int dc = 0; dc < 5; ++dc) {
            const int n = dr * 5 + dc;
            const int npx = (r + dr) * HT + (c + dc);
            const float N2n = sh_q[npx] + CEPS2;
            const float sim = (D[n] + CEPS2) * rsqrtf(N2n * N2c);
            lg[n] = TEMP * sim;
            m = fmaxf(m, lg[n]);
        }
    }
    float wei[25];
    float sum = 0.f;
#pragma unroll
    for (int n = 0; n < 25; ++n) {
        wei[n] = __expf(lg[n] - m);
        sum += wei[n];
    }
    const float rs = 1.f / sum;
#pragma unroll
    for (int n = 0; n < 25; ++n) wei[n] *= rs;

    // ---- Phase 2: weighted sums, v_pk_fma_f16 (EPS added at final cvt) ----
    h2v acc2[16];
#pragma unroll
    for (int i = 0; i < 16; ++i) acc2[i] = (h2v){(h16)0.f, (h16)0.f};
#pragma unroll
    for (int dr = 0; dr < 5; ++dr) {
#pragma unroll
        for (int dc = 0; dc < 5; ++dc) {
            const int npx = (r + dr) * HT + (c + dc);
            const h16 wh = (h16)wei[dr * 5 + dc];
            const h2v w2 = {wh, wh};
#pragma unroll
            for (int g = 0; g < 4; ++g) {
                H8 a; a.v = tile[4 * half + g][npx];
#pragma unroll
                for (int j = 0; j < 4; ++j)
                    acc2[g * 4 + j] = a.p[j] * w2 + acc2[g * 4 + j];
            }
        }
    }

    const size_t obase = (size_t)b * (CCH * HWSZ)
                       + (size_t)(32 * half) * HWSZ
                       + (h0 + r) * WW + (w0 + c);
#pragma unroll
    for (int i = 0; i < 16; ++i) {
        out[obase + (size_t)(2 * i) * HWSZ]     = (float)acc2[i][0] + EPS;
        out[obase + (size_t)(2 * i + 1) * HWSZ] = (float)acc2[i][1] + EPS;
    }
}

extern "C" void kernel_launch(void* const* d_in, const int* in_sizes, int n_in,
                              void* d_out, int out_size, void* d_ws, size_t ws_size,
                              hipStream_t stream) {
    const float* x = (const float*)d_in[0];
    float* outp = (float*)d_out;
    h16* xt = (h16*)d_ws;    // 4*128*128*64*2 B = 8.4 MB

    rv_transpose<<<dim3(HH, 4), dim3(256), 0, stream>>>(x, xt);
    rv_fused<<<dim3(WW / IT, HH / IT, 4), dim3(128, 1, 1), 0, stream>>>(xt, outp);
}

// Round 8
// 82.446 us; speedup vs baseline: 1.0981x; 1.0163x over previous
//
#include <hip/hip_runtime.h>

#define EPS 1e-5f
#define TEMP 50.0f
#define CCH 64
#define HH 128
#define WW 128
#define HWSZ (HH * WW)
#define CEPS2 (CCH * EPS * EPS)

#define IT 8            // interior tile: 8x8 pixels
#define HT 12           // halo tile: 12x12
#define HPX (HT * HT)   // 144 halo pixels
#define HPAD 145        // HPAD % 4 == 1: quarter stride 2*HPAD*4 words == 8
                        // mod 32 -> 8-lane groups (2 px x 4 quarters) cover
                        // all 32 banks: conflict-free b128

typedef _Float16 h16;
typedef h16 h2v __attribute__((ext_vector_type(2)));
typedef h16 h8v __attribute__((ext_vector_type(8)));
union H8 { h8v v; h2v p[4]; };

__device__ __forceinline__ float fdot2(h2v a, h2v b, float c) {
#if __has_builtin(__builtin_amdgcn_fdot2)
    return __builtin_amdgcn_fdot2(a, b, c, false);   // v_dot2_f32_f16
#else
    return c + (float)a[0] * (float)b[0] + (float)a[1] * (float)b[1];
#endif
}

// ---- Kernel A: [B][C][H][W] f32 -> [B][H][W][C] f16 (channel-last) ----
#define TP_PAD 72       // h16 row stride: 144 B, 16B-aligned
__global__ __launch_bounds__(256) void rv_transpose(const float* __restrict__ x,
                                                    h16* __restrict__ xt) {
    __shared__ h16 buf[WW][TP_PAD];          // 18432 B
    const int t = threadIdx.x;
    const int h = blockIdx.x;
    const int b = blockIdx.y;
    const float* src = x + (size_t)b * (CCH * HWSZ) + h * WW;
#pragma unroll 8
    for (int i = 0; i < 32; ++i) {           // 64 ch x 128 w / 256 threads
        int k = i * 256 + t;
        int c = k >> 7;                      // coalesced: w fast across lanes
        int w = k & 127;
        buf[w][c] = (h16)src[(size_t)c * HWSZ + w];
    }
    __syncthreads();
    h16* dst = xt + (size_t)(b * HH + h) * WW * CCH;
#pragma unroll
    for (int j = 0; j < 4; ++j) {            // 128 px x 8 quads / 256 threads
        int idx = j * 256 + t;
        int w = idx >> 3;
        int q = idx & 7;                     // q fast: contiguous b128 stores
        h8v v = *(const h8v*)&buf[w][q * 8];
        *(h8v*)&dst[(size_t)w * CCH + q * 8] = v;
    }
}

// ---- Kernel B: fused one-pass online-softmax accumulation ----
// Block: 256 threads = 4 waves. thread t -> pixel (t>>2), channel-quarter
// (t&3, 16 ch). Softmax max is EXACTLY the center logit (sim<=1 by
// Cauchy-Schwarz, center sim==1), so weights are final on first visit:
// each neighbor's channels are read from LDS exactly once.
__global__ __launch_bounds__(256) void rv_fused(const h16* __restrict__ xt,
                                                float* __restrict__ out) {
    __shared__ h8v  tile[8][HPAD];   // 18560 B
    __shared__ float sh_q[HPX];      // 576 B

    const int t  = threadIdx.x;
    const int w0 = blockIdx.x * IT;
    const int h0 = blockIdx.y * IT;
    const int b  = blockIdx.z;

    // ---- Stage: 144 px x 8 quads. 8-lane group = one pixel's 128 B
    // contiguous global read; LDS write banks 4q..4q+3 -> all 32. ----
#pragma unroll
    for (int it = 0; it < 5; ++it) {
        int k = it * 256 + t;
        if (k < 8 * HPX) {
            int q  = k & 7;
            int px = k >> 3;             // 0..143
            int row = px / HT;
            int col = px - row * HT;
            int gh = h0 + row - 2;
            int gw = w0 + col - 2;
            h8v v = {};
            if (gh >= 0 && gh < HH && gw >= 0 && gw < WW) {
                v = *(const h8v*)&xt[((size_t)(b * HH + gh) * WW + gw) * CCH + q * 8];
            }
            tile[q][px] = v;
        }
    }
    __syncthreads();

    // ---- Per-halo-pixel sumsq (from the SAME rounded f16 values) ----
    if (t < HPX) {
        float q = 0.f;
#pragma unroll
        for (int hq = 0; hq < 8; ++hq) {
            H8 u; u.v = tile[hq][t];
#pragma unroll
            for (int j = 0; j < 4; ++j) q = fdot2(u.p[j], u.p[j], q);
        }
        sh_q[t] = q;
    }
    __syncthreads();

    const int qg  = t & 3;               // channel quarter: quads 2qg, 2qg+1
    const int pix = t >> 2;              // 0..63
    const int r   = pix >> 3;
    const int cl  = pix & 7;
    const int cpx = (r + 2) * HT + (cl + 2);

    const float rinvC = rsqrtf(sh_q[cpx] + CEPS2);

    H8 ctr0, ctr1;
    ctr0.v = tile[2 * qg][cpx];
    ctr1.v = tile[2 * qg + 1][cpx];

    h2v acc[8] = {};                     // unnormalized numerator, 16 ch
    float wsum = 0.f;

#pragma unroll
    for (int dr = 0; dr < 5; ++dr) {
#pragma unroll
        for (int dc = 0; dc < 5; ++dc) {
            const int npx = (r + dr) * HT + (cl + dc);
            H8 a0, a1;
            a0.v = tile[2 * qg][npx];
            a1.v = tile[2 * qg + 1][npx];
            // partial dot over this quarter's 16 channels
            float d = 0.f;
#pragma unroll
            for (int j = 0; j < 4; ++j) d = fdot2(ctr0.p[j], a0.p[j], d);
#pragma unroll
            for (int j = 0; j < 4; ++j) d = fdot2(ctr1.p[j], a1.p[j], d);
            // full 64-ch dot: butterfly over the 4 quarter-lanes
            d += __shfl_xor(d, 1);
            d += __shfl_xor(d, 2);
            // weight: exp(TEMP*sim - TEMP), max == center logit exactly
            const float N2n = sh_q[npx] + CEPS2;
            const float sim = (d + CEPS2) * (rsqrtf(N2n) * rinvC);
            const float wn = __expf(fmaf(TEMP, sim, -TEMP));
            wsum += wn;
            const h16 wh = (h16)wn;
            const h2v w2 = {wh, wh};
#pragma unroll
            for (int j = 0; j < 4; ++j) {
                acc[j]     = a0.p[j] * w2 + acc[j];
                acc[4 + j] = a1.p[j] * w2 + acc[4 + j];
            }
        }
    }

    // ---- Normalize + store this quarter's 16 channels ----
    const float rs = 1.f / wsum;
    const size_t obase = (size_t)b * (CCH * HWSZ)
                       + (size_t)(qg * 16) * HWSZ
                       + (h0 + r) * WW + (w0 + cl);
#pragma unroll
    for (int g = 0; g < 2; ++g) {
#pragma unroll
        for (int j = 0; j < 4; ++j) {
            const float f0 = (float)acc[g * 4 + j][0];
            const float f1 = (float)acc[g * 4 + j][1];
            out[obase + (size_t)(g * 8 + 2 * j) * HWSZ]     = fmaf(f0, rs, EPS);
            out[obase + (size_t)(g * 8 + 2 * j + 1) * HWSZ] = fmaf(f1, rs, EPS);
        }
    }
}

extern "C" void kernel_launch(void* const* d_in, const int* in_sizes, int n_in,
                              void* d_out, int out_size, void* d_ws, size_t ws_size,
                              hipStream_t stream) {
    const float* x = (const float*)d_in[0];
    float* outp = (float*)d_out;
    h16* xt = (h16*)d_ws;    // 4*128*128*64*2 B = 8.4 MB

    rv_transpose<<<dim3(HH, 4), dim3(256), 0, stream>>>(x, xt);
    rv_fused<<<dim3(WW / IT, HH / IT, 4), dim3(256, 1, 1), 0, stream>>>(xt, outp);
}